// Round 1
// baseline (565.774 us; speedup 1.0000x reference)
//
#include <hip/hip_runtime.h>
#include <cstdint>
#include <cstddef>

// Problem constants (B=4, T=2048, C=1024, H=16, S=64)
#define TT 2048
#define CC 1024
#define HH 16
#define SS 64
#define MROWS 8192  // B*T

using short8 = __attribute__((ext_vector_type(8))) short;
using f32x4  = __attribute__((ext_vector_type(4))) float;

__device__ __forceinline__ float b2f(unsigned short u) {
  union { unsigned int i; float f; } c; c.i = ((unsigned int)u) << 16; return c.f;
}
__device__ __forceinline__ unsigned short f2b(float f) {
  union { float f; unsigned int i; } c; c.f = f;
  unsigned int r = c.i + 0x7fffu + ((c.i >> 16) & 1u);  // RNE; inputs finite
  return (unsigned short)(r >> 16);
}

// ---------------- fp32 -> bf16 weight conversion ----------------
__global__ __launch_bounds__(256) void cvt_kernel(const float* __restrict__ in,
                                                  unsigned short* __restrict__ out, int n) {
  int i = (blockIdx.x * 256 + threadIdx.x) * 4;
  if (i >= n) return;
  float4 v = *(const float4*)(in + i);
  ushort4 o = make_ushort4(f2b(v.x), f2b(v.y), f2b(v.z), f2b(v.w));
  *(ushort4*)(out + i) = o;
}

// ---------------- LayerNorm (fp32 in, bf16 out), one block per row ----------------
__global__ __launch_bounds__(256) void ln_kernel(const float* __restrict__ x,
                                                 const float* __restrict__ g,
                                                 const float* __restrict__ bta,
                                                 unsigned short* __restrict__ out) {
  const int row = blockIdx.x;
  const int tid = threadIdx.x;
  const float* xr = x + (size_t)row * CC;
  float4 v = *(const float4*)(xr + tid * 4);
  float s  = v.x + v.y + v.z + v.w;
  float ss = v.x * v.x + v.y * v.y + v.z * v.z + v.w * v.w;
#pragma unroll
  for (int off = 32; off > 0; off >>= 1) {
    s  += __shfl_xor(s, off, 64);
    ss += __shfl_xor(ss, off, 64);
  }
  __shared__ float ls[4], lss[4];
  if ((tid & 63) == 0) { ls[tid >> 6] = s; lss[tid >> 6] = ss; }
  __syncthreads();
  s  = ls[0] + ls[1] + ls[2] + ls[3];
  ss = lss[0] + lss[1] + lss[2] + lss[3];
  const float mean = s * (1.0f / CC);
  const float var  = ss * (1.0f / CC) - mean * mean;
  const float rstd = rsqrtf(var + 1e-5f);
  float4 gv = *(const float4*)(g + tid * 4);
  float4 bv = *(const float4*)(bta + tid * 4);
  ushort4 o = make_ushort4(f2b((v.x - mean) * rstd * gv.x + bv.x),
                           f2b((v.y - mean) * rstd * gv.y + bv.y),
                           f2b((v.z - mean) * rstd * gv.z + bv.z),
                           f2b((v.w - mean) * rstd * gv.w + bv.w));
  *(ushort4*)(out + (size_t)row * CC + tid * 4) = o;
}

// ---------------- WKV chunked parallel scan, fused sigmoid(r)*wkv ----------------
// grid = B*H blocks, block = 1024 threads: s = tid&63, chunk c = tid>>6 (16 chunks of 128)
__global__ __launch_bounds__(1024) void wkv_kernel(const unsigned short* __restrict__ kb,
                                                   const unsigned short* __restrict__ vb,
                                                   const unsigned short* __restrict__ rb,
                                                   const float* __restrict__ td,
                                                   const float* __restrict__ tfp,
                                                   unsigned short* __restrict__ rwkv) {
  const int bh = blockIdx.x;
  const int b  = bh / HH, h = bh % HH;
  const int s  = threadIdx.x & 63;
  const int c  = threadIdx.x >> 6;  // 0..15
  const int L  = TT / 16;           // 128
  const int ch = h * SS + s;
  const float e    = __expf(td[ch]);
  const float d    = __expf(-e);          // per-step decay
  const float Dc   = __expf(-e * (float)L); // per-chunk decay d^L
  const float tfir = __expf(tfp[ch]);
  const size_t base = ((size_t)b * TT + (size_t)c * L) * CC + ch;

  __shared__ float lnum[16][SS];
  __shared__ float lden[16][SS];

  // phase 1: local decayed sums with zero carry-in
  float num = 0.f, den = 0.f;
  {
    size_t idx = base;
    for (int i = 0; i < L; ++i) {
      float kk = b2f(kb[idx]);
      float w  = __expf(fminf(kk, 30.f));
      if (c == 0 && i == 0) w *= tfir;  // time_first seeding at t==0
      float vv = b2f(vb[idx]);
      num = d * num + w * vv;
      den = d * den + w;
      idx += CC;
    }
  }
  lnum[c][s] = num; lden[c][s] = den;
  __syncthreads();

  // chunk-carry serial scan (64 threads, one per s), in-place: lnum becomes carry-in
  if (threadIdx.x < 64) {
    float rn = 0.f, rd = 0.f;
    for (int cc2 = 0; cc2 < 16; ++cc2) {
      float tn = lnum[cc2][s], tdn = lden[cc2][s];
      lnum[cc2][s] = rn; lden[cc2][s] = rd;
      rn = Dc * rn + tn;
      rd = Dc * rd + tdn;
    }
  }
  __syncthreads();

  // phase 2: replay with carry-in, emit sigmoid(r)*wkv
  num = lnum[c][s]; den = lden[c][s];
  {
    size_t idx = base;
    for (int i = 0; i < L; ++i) {
      float kk = b2f(kb[idx]);
      float w  = __expf(fminf(kk, 30.f));
      if (c == 0 && i == 0) w *= tfir;
      float vv = b2f(vb[idx]);
      num = d * num + w * vv;
      den = d * den + w;
      float o  = num / (den + 1e-6f);
      float rr = b2f(rb[idx]);
      float sg = 1.0f / (1.0f + __expf(-rr));
      rwkv[idx] = f2b(sg * o);
      idx += CC;
    }
  }
}

// ---------------- bf16 MFMA GEMM: C[M,N] = A[M,K] @ Bw[N,K]^T ----------------
// EP=0: bf16 store; EP=1: relu^2 -> bf16; EP=2: fp32 store with residual add
template <int EP>
__global__ __launch_bounds__(256) void gemm_bt(const unsigned short* __restrict__ A,
                                               const unsigned short* __restrict__ Bw,
                                               void* __restrict__ outv,
                                               const float* __restrict__ res,
                                               int N, int K) {
  __shared__ __align__(16) unsigned short As[128 * 32];
  __shared__ __align__(16) unsigned short Bs[128 * 32];
  const int tid = threadIdx.x;
  const int bn = blockIdx.x, bm = blockIdx.y;

  // staging: 512 16B-chunks per tile, 2 per thread; chunk c -> row c>>2, col (c&3)*8
  const int r0 = tid >> 2;
  const int c0 = (tid & 3) * 8;
  const int r1 = r0 + 64;  // tid+256 chunk
  const unsigned short* ga0 = A  + (size_t)(bm * 128 + r0) * K + c0;
  const unsigned short* ga1 = A  + (size_t)(bm * 128 + r1) * K + c0;
  const unsigned short* gb0 = Bw + (size_t)(bn * 128 + r0) * K + c0;
  const unsigned short* gb1 = Bw + (size_t)(bn * 128 + r1) * K + c0;
  uint4* sa0 = (uint4*)(As + r0 * 32 + c0);
  uint4* sa1 = (uint4*)(As + r1 * 32 + c0);
  uint4* sb0 = (uint4*)(Bs + r0 * 32 + c0);
  uint4* sb1 = (uint4*)(Bs + r1 * 32 + c0);

  const int lane = tid & 63;
  const int w    = tid >> 6;
  const int q    = lane >> 4, r16 = lane & 15;
  const int wrow = (w >> 1) * 64, wcol = (w & 1) * 64;

  f32x4 acc[4][4] = {};

  for (int k0 = 0; k0 < K; k0 += 32) {
    uint4 va0 = *(const uint4*)ga0;
    uint4 va1 = *(const uint4*)ga1;
    uint4 vb0 = *(const uint4*)gb0;
    uint4 vb1 = *(const uint4*)gb1;
    ga0 += 32; ga1 += 32; gb0 += 32; gb1 += 32;
    __syncthreads();  // previous iteration's reads done
    *sa0 = va0; *sa1 = va1; *sb0 = vb0; *sb1 = vb1;
    __syncthreads();  // tiles visible

    short8 af[4], bfr[4];
#pragma unroll
    for (int mi = 0; mi < 4; ++mi)
      af[mi] = *(const short8*)(As + (wrow + mi * 16 + r16) * 32 + q * 8);
#pragma unroll
    for (int ni = 0; ni < 4; ++ni)
      bfr[ni] = *(const short8*)(Bs + (wcol + ni * 16 + r16) * 32 + q * 8);
#pragma unroll
    for (int mi = 0; mi < 4; ++mi)
#pragma unroll
      for (int ni = 0; ni < 4; ++ni)
        acc[mi][ni] = __builtin_amdgcn_mfma_f32_16x16x32_bf16(af[mi], bfr[ni], acc[mi][ni], 0, 0, 0);
  }

  // epilogue: D[m = quad*4+reg][n = lane&15]
#pragma unroll
  for (int mi = 0; mi < 4; ++mi) {
#pragma unroll
    for (int r = 0; r < 4; ++r) {
      const int grow = bm * 128 + wrow + mi * 16 + q * 4 + r;
#pragma unroll
      for (int ni = 0; ni < 4; ++ni) {
        const int gcol = bn * 128 + wcol + ni * 16 + r16;
        const size_t idx = (size_t)grow * N + gcol;
        float vv = acc[mi][ni][r];
        if (EP == 2) {
          ((float*)outv)[idx] = res[idx] + vv;
        } else {
          if (EP == 1) { vv = fmaxf(vv, 0.0f); vv = vv * vv; }
          ((unsigned short*)outv)[idx] = f2b(vv);
        }
      }
    }
  }
}

extern "C" void kernel_launch(void* const* d_in, const int* in_sizes, int n_in,
                              void* d_out, int out_size, void* d_ws, size_t ws_size,
                              hipStream_t stream) {
  const float* x    = (const float*)d_in[0];
  const float* td   = (const float*)d_in[1];
  const float* tf   = (const float*)d_in[2];
  const float* Wk   = (const float*)d_in[3];
  const float* Wv   = (const float*)d_in[4];
  const float* Wr   = (const float*)d_in[5];
  const float* Wo   = (const float*)d_in[6];
  const float* Wffk = (const float*)d_in[7];
  const float* Wffv = (const float*)d_in[8];
  const float* g1   = (const float*)d_in[9];
  const float* b1   = (const float*)d_in[10];
  const float* g2   = (const float*)d_in[11];
  const float* b2   = (const float*)d_in[12];
  float* out = (float*)d_out;

  char* ws = (char*)d_ws;
  const size_t MB = 1024ull * 1024ull;
  unsigned short* WkB  = (unsigned short*)(ws + 0 * MB);    // 2 MB
  unsigned short* WvB  = (unsigned short*)(ws + 2 * MB);    // 2 MB
  unsigned short* WrB  = (unsigned short*)(ws + 4 * MB);    // 2 MB
  unsigned short* WoB  = (unsigned short*)(ws + 6 * MB);    // 2 MB
  unsigned short* WfkB = (unsigned short*)(ws + 8 * MB);    // 8 MB
  unsigned short* WfvB = (unsigned short*)(ws + 16 * MB);   // 8 MB
  unsigned short* xl   = (unsigned short*)(ws + 24 * MB);   // 16 MB (reused as rwkv)
  unsigned short* kb   = (unsigned short*)(ws + 40 * MB);   // 16 MB (reused as xl2)
  unsigned short* vb   = (unsigned short*)(ws + 56 * MB);   // 16 MB
  unsigned short* rb   = (unsigned short*)(ws + 72 * MB);   // 16 MB
  float*          x2   = (float*)(ws + 88 * MB);            // 32 MB
  unsigned short* hb   = (unsigned short*)(ws + 120 * MB);  // 64 MB -> total 184 MB
  unsigned short* rwkv = xl;  // xl dead after r GEMM
  unsigned short* xl2  = kb;  // kb dead after WKV

  // weights -> bf16
  cvt_kernel<<<1024, 256, 0, stream>>>(Wk, WkB, 1024 * 1024);
  cvt_kernel<<<1024, 256, 0, stream>>>(Wv, WvB, 1024 * 1024);
  cvt_kernel<<<1024, 256, 0, stream>>>(Wr, WrB, 1024 * 1024);
  cvt_kernel<<<1024, 256, 0, stream>>>(Wo, WoB, 1024 * 1024);
  cvt_kernel<<<4096, 256, 0, stream>>>(Wffk, WfkB, 4096 * 1024);
  cvt_kernel<<<4096, 256, 0, stream>>>(Wffv, WfvB, 4096 * 1024);

  // LN1
  ln_kernel<<<MROWS, 256, 0, stream>>>(x, g1, b1, xl);

  // k, v, r GEMMs
  dim3 gk(1024 / 128, MROWS / 128);
  gemm_bt<0><<<gk, 256, 0, stream>>>(xl, WkB, kb, nullptr, 1024, 1024);
  gemm_bt<0><<<gk, 256, 0, stream>>>(xl, WvB, vb, nullptr, 1024, 1024);
  gemm_bt<0><<<gk, 256, 0, stream>>>(xl, WrB, rb, nullptr, 1024, 1024);

  // WKV + sigmoid(r) fuse
  wkv_kernel<<<4 * HH, 1024, 0, stream>>>(kb, vb, rb, td, tf, rwkv);

  // x2 = x + rwkv @ Wo^T
  gemm_bt<2><<<gk, 256, 0, stream>>>(rwkv, WoB, x2, x, 1024, 1024);

  // LN2
  ln_kernel<<<MROWS, 256, 0, stream>>>(x2, g2, b2, xl2);

  // h = relu(xl2 @ Wffk^T)^2
  gemm_bt<1><<<dim3(4096 / 128, MROWS / 128), 256, 0, stream>>>(xl2, WfkB, hb, nullptr, 4096, 1024);

  // out = x2 + h @ Wffv^T
  gemm_bt<2><<<gk, 256, 0, stream>>>(hb, WfvB, out, x2, 1024, 4096);
}

// Round 2
// 551.866 us; speedup vs baseline: 1.0252x; 1.0252x over previous
//
#include <hip/hip_runtime.h>
#include <cstdint>
#include <cstddef>

// Problem constants (B=4, T=2048, C=1024, H=16, S=64)
#define TT 2048
#define CC 1024
#define HH 16
#define SS 64
#define MROWS 8192  // B*T

using short8 = __attribute__((ext_vector_type(8))) short;
using f32x4  = __attribute__((ext_vector_type(4))) float;

__device__ __forceinline__ float b2f(unsigned short u) {
  union { unsigned int i; float f; } c; c.i = ((unsigned int)u) << 16; return c.f;
}
__device__ __forceinline__ unsigned short f2b(float f) {
  union { float f; unsigned int i; } c; c.f = f;
  unsigned int r = c.i + 0x7fffu + ((c.i >> 16) & 1u);  // RNE; inputs finite
  return (unsigned short)(r >> 16);
}

// async global->LDS, 16 bytes per lane (wave-uniform LDS base + lane*16)
typedef const __attribute__((address_space(1))) unsigned int* gas_ptr;
typedef __attribute__((address_space(3))) unsigned int* las_ptr;
__device__ __forceinline__ void gl_lds16(const unsigned short* g, unsigned short* l) {
  __builtin_amdgcn_global_load_lds((gas_ptr)g, (las_ptr)l, 16, 0, 0);
}

// ---------------- fp32 -> bf16 weight conversion ----------------
__global__ __launch_bounds__(256) void cvt_kernel(const float* __restrict__ in,
                                                  unsigned short* __restrict__ out, int n) {
  int i = (blockIdx.x * 256 + threadIdx.x) * 4;
  if (i >= n) return;
  float4 v = *(const float4*)(in + i);
  ushort4 o = make_ushort4(f2b(v.x), f2b(v.y), f2b(v.z), f2b(v.w));
  *(ushort4*)(out + i) = o;
}

// ---------------- LayerNorm (fp32 in, bf16 out), one block per row ----------------
__global__ __launch_bounds__(256) void ln_kernel(const float* __restrict__ x,
                                                 const float* __restrict__ g,
                                                 const float* __restrict__ bta,
                                                 unsigned short* __restrict__ out) {
  const int row = blockIdx.x;
  const int tid = threadIdx.x;
  const float* xr = x + (size_t)row * CC;
  float4 v = *(const float4*)(xr + tid * 4);
  float s  = v.x + v.y + v.z + v.w;
  float ss = v.x * v.x + v.y * v.y + v.z * v.z + v.w * v.w;
#pragma unroll
  for (int off = 32; off > 0; off >>= 1) {
    s  += __shfl_xor(s, off, 64);
    ss += __shfl_xor(ss, off, 64);
  }
  __shared__ float ls[4], lss[4];
  if ((tid & 63) == 0) { ls[tid >> 6] = s; lss[tid >> 6] = ss; }
  __syncthreads();
  s  = ls[0] + ls[1] + ls[2] + ls[3];
  ss = lss[0] + lss[1] + lss[2] + lss[3];
  const float mean = s * (1.0f / CC);
  const float var  = ss * (1.0f / CC) - mean * mean;
  const float rstd = rsqrtf(var + 1e-5f);
  float4 gv = *(const float4*)(g + tid * 4);
  float4 bv = *(const float4*)(bta + tid * 4);
  ushort4 o = make_ushort4(f2b((v.x - mean) * rstd * gv.x + bv.x),
                           f2b((v.y - mean) * rstd * gv.y + bv.y),
                           f2b((v.z - mean) * rstd * gv.z + bv.z),
                           f2b((v.w - mean) * rstd * gv.w + bv.w));
  *(ushort4*)(out + (size_t)row * CC + tid * 4) = o;
}

// ---------------- WKV chunked parallel scan, fused sigmoid(r)*wkv ----------------
// Reads fused kvr buffer [M, 3072]: k = cols 0..1023, v = 1024..2047, r = 2048..3071.
// grid = B*H blocks, block = 1024 threads: s = tid&63, chunk c = tid>>6 (16 chunks of 128)
#define KVRN 3072
__global__ __launch_bounds__(1024) void wkv_kernel(const unsigned short* __restrict__ kvr,
                                                   const float* __restrict__ td,
                                                   const float* __restrict__ tfp,
                                                   unsigned short* __restrict__ rwkv) {
  const int bh = blockIdx.x;
  const int b  = bh / HH, h = bh % HH;
  const int s  = threadIdx.x & 63;
  const int c  = threadIdx.x >> 6;  // 0..15
  const int L  = TT / 16;           // 128
  const int ch = h * SS + s;
  const float e    = __expf(td[ch]);
  const float d    = __expf(-e);            // per-step decay
  const float Dc   = __expf(-e * (float)L); // per-chunk decay d^L
  const float tfir = __expf(tfp[ch]);
  const size_t row0 = (size_t)b * TT + (size_t)c * L;
  const size_t base = row0 * KVRN + ch;

  __shared__ float lnum[16][SS];
  __shared__ float lden[16][SS];

  // phase 1: local decayed sums with zero carry-in
  float num = 0.f, den = 0.f;
  {
    size_t idx = base;
    for (int i = 0; i < L; ++i) {
      float kk = b2f(kvr[idx]);
      float w  = __expf(fminf(kk, 30.f));
      if (c == 0 && i == 0) w *= tfir;  // time_first seeding at t==0
      float vv = b2f(kvr[idx + 1024]);
      num = d * num + w * vv;
      den = d * den + w;
      idx += KVRN;
    }
  }
  lnum[c][s] = num; lden[c][s] = den;
  __syncthreads();

  // chunk-carry serial scan (64 threads, one per s), in-place: lnum becomes carry-in
  if (threadIdx.x < 64) {
    float rn = 0.f, rd = 0.f;
    for (int cc2 = 0; cc2 < 16; ++cc2) {
      float tn = lnum[cc2][s], tdn = lden[cc2][s];
      lnum[cc2][s] = rn; lden[cc2][s] = rd;
      rn = Dc * rn + tn;
      rd = Dc * rd + tdn;
    }
  }
  __syncthreads();

  // phase 2: replay with carry-in, emit sigmoid(r)*wkv
  num = lnum[c][s]; den = lden[c][s];
  {
    size_t idx = base;
    size_t odx = row0 * CC + ch;
    for (int i = 0; i < L; ++i) {
      float kk = b2f(kvr[idx]);
      float w  = __expf(fminf(kk, 30.f));
      if (c == 0 && i == 0) w *= tfir;
      float vv = b2f(kvr[idx + 1024]);
      num = d * num + w * vv;
      den = d * den + w;
      float o  = num / (den + 1e-6f);
      float rr = b2f(kvr[idx + 2048]);
      float sg = 1.0f / (1.0f + __expf(-rr));
      rwkv[odx] = f2b(sg * o);
      idx += KVRN;
      odx += CC;
    }
  }
}

// ---------------- bf16 MFMA GEMM: C[M,N] = A[M,K] @ Bw[N,K]^T ----------------
// m97 structure: 128x128 tile, BK=32, global_load_lds width=16 staging, 2-barrier K-loop.
// EP=0: bf16 store; EP=1: relu^2 -> bf16; EP=2: fp32 store with residual add
template <int EP>
__global__ __launch_bounds__(256) void gemm_bt(const unsigned short* __restrict__ A,
                                               const unsigned short* __restrict__ Bw,
                                               void* __restrict__ outv,
                                               const float* __restrict__ res,
                                               int N, int K) {
  __shared__ __align__(16) unsigned short As[128 * 32];
  __shared__ __align__(16) unsigned short Bs[128 * 32];
  const int tid = threadIdx.x;
  const int bn = blockIdx.x, bm = blockIdx.y;

  // 512 16B chunks per 8KB tile; chunk c -> LDS byte offset c*16, row c>>2, colgroup c&3
  const int ch0 = tid;        // chunks 0..255
  const int ch1 = tid + 256;  // chunks 256..511
  const int r0 = ch0 >> 2, q0 = ch0 & 3;
  const int r1 = ch1 >> 2, q1 = ch1 & 3;
  const unsigned short* ga0 = A  + (size_t)(bm * 128 + r0) * K + q0 * 8;
  const unsigned short* ga1 = A  + (size_t)(bm * 128 + r1) * K + q1 * 8;
  const unsigned short* gb0 = Bw + (size_t)(bn * 128 + r0) * K + q0 * 8;
  const unsigned short* gb1 = Bw + (size_t)(bn * 128 + r1) * K + q1 * 8;
  unsigned short* sa0 = As + ch0 * 8;
  unsigned short* sa1 = As + ch1 * 8;
  unsigned short* sb0 = Bs + ch0 * 8;
  unsigned short* sb1 = Bs + ch1 * 8;

  const int lane = tid & 63;
  const int w    = tid >> 6;
  const int q    = lane >> 4, r16 = lane & 15;
  const int wrow = (w >> 1) * 64, wcol = (w & 1) * 64;

  f32x4 acc[4][4] = {};

  for (int k0 = 0; k0 < K; k0 += 32) {
    // async stage this iteration's tiles into LDS (no VGPR round-trip)
    gl_lds16(ga0, sa0);
    gl_lds16(ga1, sa1);
    gl_lds16(gb0, sb0);
    gl_lds16(gb1, sb1);
    ga0 += 32; ga1 += 32; gb0 += 32; gb1 += 32;
    __syncthreads();  // drains vmcnt (loads landed) + all waves arrived

    short8 af[4], bfr[4];
#pragma unroll
    for (int mi = 0; mi < 4; ++mi)
      af[mi] = *(const short8*)(As + (wrow + mi * 16 + r16) * 32 + q * 8);
#pragma unroll
    for (int ni = 0; ni < 4; ++ni)
      bfr[ni] = *(const short8*)(Bs + (wcol + ni * 16 + r16) * 32 + q * 8);
#pragma unroll
    for (int mi = 0; mi < 4; ++mi)
#pragma unroll
      for (int ni = 0; ni < 4; ++ni)
        acc[mi][ni] = __builtin_amdgcn_mfma_f32_16x16x32_bf16(af[mi], bfr[ni], acc[mi][ni], 0, 0, 0);

    __syncthreads();  // protect LDS before next iteration's async stores
  }

  // epilogue: D[m = quad*4+reg][n = lane&15]
#pragma unroll
  for (int mi = 0; mi < 4; ++mi) {
#pragma unroll
    for (int r = 0; r < 4; ++r) {
      const int grow = bm * 128 + wrow + mi * 16 + q * 4 + r;
#pragma unroll
      for (int ni = 0; ni < 4; ++ni) {
        const int gcol = bn * 128 + wcol + ni * 16 + r16;
        const size_t idx = (size_t)grow * N + gcol;
        float vv = acc[mi][ni][r];
        if (EP == 2) {
          ((float*)outv)[idx] = res[idx] + vv;
        } else {
          if (EP == 1) { vv = fmaxf(vv, 0.0f); vv = vv * vv; }
          ((unsigned short*)outv)[idx] = f2b(vv);
        }
      }
    }
  }
}

extern "C" void kernel_launch(void* const* d_in, const int* in_sizes, int n_in,
                              void* d_out, int out_size, void* d_ws, size_t ws_size,
                              hipStream_t stream) {
  const float* x    = (const float*)d_in[0];
  const float* td   = (const float*)d_in[1];
  const float* tf   = (const float*)d_in[2];
  const float* Wk   = (const float*)d_in[3];
  const float* Wv   = (const float*)d_in[4];
  const float* Wr   = (const float*)d_in[5];
  const float* Wo   = (const float*)d_in[6];
  const float* Wffk = (const float*)d_in[7];
  const float* Wffv = (const float*)d_in[8];
  const float* g1   = (const float*)d_in[9];
  const float* b1   = (const float*)d_in[10];
  const float* g2   = (const float*)d_in[11];
  const float* b2   = (const float*)d_in[12];
  float* out = (float*)d_out;

  char* ws = (char*)d_ws;
  const size_t MB = 1024ull * 1024ull;
  unsigned short* WkvrB = (unsigned short*)(ws + 0 * MB);   // 6 MB [3072,1024] bf16
  unsigned short* WoB   = (unsigned short*)(ws + 6 * MB);   // 2 MB
  unsigned short* WfkB  = (unsigned short*)(ws + 8 * MB);   // 8 MB
  unsigned short* WfvB  = (unsigned short*)(ws + 16 * MB);  // 8 MB
  unsigned short* xl    = (unsigned short*)(ws + 24 * MB);  // 16 MB (reused as rwkv)
  unsigned short* kvr   = (unsigned short*)(ws + 40 * MB);  // 48 MB [8192,3072] (reused as xl2)
  float*          x2    = (float*)(ws + 88 * MB);           // 32 MB
  unsigned short* hb    = (unsigned short*)(ws + 120 * MB); // 64 MB -> total 184 MB
  unsigned short* rwkv  = xl;   // xl dead after kvr GEMM
  unsigned short* xl2   = kvr;  // kvr dead after WKV

  // weights -> bf16 (k,v,r concatenated into one [3072,1024] buffer)
  cvt_kernel<<<1024, 256, 0, stream>>>(Wk, WkvrB, 1024 * 1024);
  cvt_kernel<<<1024, 256, 0, stream>>>(Wv, WkvrB + 1024 * 1024, 1024 * 1024);
  cvt_kernel<<<1024, 256, 0, stream>>>(Wr, WkvrB + 2 * 1024 * 1024, 1024 * 1024);
  cvt_kernel<<<1024, 256, 0, stream>>>(Wo, WoB, 1024 * 1024);
  cvt_kernel<<<4096, 256, 0, stream>>>(Wffk, WfkB, 4096 * 1024);
  cvt_kernel<<<4096, 256, 0, stream>>>(Wffv, WfvB, 4096 * 1024);

  // LN1
  ln_kernel<<<MROWS, 256, 0, stream>>>(x, g1, b1, xl);

  // fused k|v|r GEMM: kvr[M,3072] = xl @ WkvrB^T
  gemm_bt<0><<<dim3(KVRN / 128, MROWS / 128), 256, 0, stream>>>(xl, WkvrB, kvr, nullptr, KVRN, 1024);

  // WKV + sigmoid(r) fuse
  wkv_kernel<<<4 * HH, 1024, 0, stream>>>(kvr, td, tf, rwkv);

  // x2 = x + rwkv @ Wo^T
  dim3 gk(1024 / 128, MROWS / 128);
  gemm_bt<2><<<gk, 256, 0, stream>>>(rwkv, WoB, x2, x, 1024, 1024);

  // LN2
  ln_kernel<<<MROWS, 256, 0, stream>>>(x2, g2, b2, xl2);

  // h = relu(xl2 @ Wffk^T)^2
  gemm_bt<1><<<dim3(4096 / 128, MROWS / 128), 256, 0, stream>>>(xl2, WfkB, hb, nullptr, 4096, 1024);

  // out = x2 + h @ Wffv^T
  gemm_bt<2><<<gk, 256, 0, stream>>>(hb, WfvB, out, x2, 1024, 4096);
}

// Round 3
// 537.459 us; speedup vs baseline: 1.0527x; 1.0268x over previous
//
#include <hip/hip_runtime.h>
#include <cstdint>
#include <cstddef>

// Problem constants (B=4, T=2048, C=1024, H=16, S=64)
#define TT 2048
#define CC 1024
#define HH 16
#define SS 64
#define MROWS 8192  // B*T

using short8 = __attribute__((ext_vector_type(8))) short;
using f32x4  = __attribute__((ext_vector_type(4))) float;

__device__ __forceinline__ float b2f(unsigned short u) {
  union { unsigned int i; float f; } c; c.i = ((unsigned int)u) << 16; return c.f;
}
__device__ __forceinline__ unsigned short f2b(float f) {
  union { float f; unsigned int i; } c; c.f = f;
  unsigned int r = c.i + 0x7fffu + ((c.i >> 16) & 1u);  // RNE; inputs finite
  return (unsigned short)(r >> 16);
}

// async global->LDS, 16 bytes per lane (wave-uniform LDS base + lane*16; global addr per-lane)
typedef const __attribute__((address_space(1))) unsigned int* gas_ptr;
typedef __attribute__((address_space(3))) unsigned int* las_ptr;
__device__ __forceinline__ void gl_lds16(const unsigned short* g, unsigned short* l) {
  __builtin_amdgcn_global_load_lds((gas_ptr)g, (las_ptr)l, 16, 0, 0);
}

// ---------------- fp32 -> bf16 weight conversion ----------------
__global__ __launch_bounds__(256) void cvt_kernel(const float* __restrict__ in,
                                                  unsigned short* __restrict__ out, int n) {
  int i = (blockIdx.x * 256 + threadIdx.x) * 4;
  if (i >= n) return;
  float4 v = *(const float4*)(in + i);
  ushort4 o = make_ushort4(f2b(v.x), f2b(v.y), f2b(v.z), f2b(v.w));
  *(ushort4*)(out + i) = o;
}

// ---------------- LayerNorm (fp32 in, bf16 out), one block per row ----------------
__global__ __launch_bounds__(256) void ln_kernel(const float* __restrict__ x,
                                                 const float* __restrict__ g,
                                                 const float* __restrict__ bta,
                                                 unsigned short* __restrict__ out) {
  const int row = blockIdx.x;
  const int tid = threadIdx.x;
  const float* xr = x + (size_t)row * CC;
  float4 v = *(const float4*)(xr + tid * 4);
  float s  = v.x + v.y + v.z + v.w;
  float ss = v.x * v.x + v.y * v.y + v.z * v.z + v.w * v.w;
#pragma unroll
  for (int off = 32; off > 0; off >>= 1) {
    s  += __shfl_xor(s, off, 64);
    ss += __shfl_xor(ss, off, 64);
  }
  __shared__ float ls[4], lss[4];
  if ((tid & 63) == 0) { ls[tid >> 6] = s; lss[tid >> 6] = ss; }
  __syncthreads();
  s  = ls[0] + ls[1] + ls[2] + ls[3];
  ss = lss[0] + lss[1] + lss[2] + lss[3];
  const float mean = s * (1.0f / CC);
  const float var  = ss * (1.0f / CC) - mean * mean;
  const float rstd = rsqrtf(var + 1e-5f);
  float4 gv = *(const float4*)(g + tid * 4);
  float4 bv = *(const float4*)(bta + tid * 4);
  ushort4 o = make_ushort4(f2b((v.x - mean) * rstd * gv.x + bv.x),
                           f2b((v.y - mean) * rstd * gv.y + bv.y),
                           f2b((v.z - mean) * rstd * gv.z + bv.z),
                           f2b((v.w - mean) * rstd * gv.w + bv.w));
  *(ushort4*)(out + (size_t)row * CC + tid * 4) = o;
}

// ---------------- WKV chunked parallel scan, fused sigmoid(r)*wkv ----------------
// Reads fused kvr buffer [M, 3072]: k = cols 0..1023, v = 1024..2047, r = 2048..3071.
// grid = B*H blocks, block = 1024 threads: s = tid&63, chunk c = tid>>6 (16 chunks of 128)
#define KVRN 3072
__global__ __launch_bounds__(1024) void wkv_kernel(const unsigned short* __restrict__ kvr,
                                                   const float* __restrict__ td,
                                                   const float* __restrict__ tfp,
                                                   unsigned short* __restrict__ rwkv) {
  const int bh = blockIdx.x;
  const int b  = bh / HH, h = bh % HH;
  const int s  = threadIdx.x & 63;
  const int c  = threadIdx.x >> 6;  // 0..15
  const int L  = TT / 16;           // 128
  const int ch = h * SS + s;
  const float e    = __expf(td[ch]);
  const float d    = __expf(-e);            // per-step decay
  const float Dc   = __expf(-e * (float)L); // per-chunk decay d^L
  const float tfir = __expf(tfp[ch]);
  const size_t row0 = (size_t)b * TT + (size_t)c * L;
  const size_t base = row0 * KVRN + ch;

  __shared__ float lnum[16][SS];
  __shared__ float lden[16][SS];

  // phase 1: local decayed sums with zero carry-in
  float num = 0.f, den = 0.f;
  {
    size_t idx = base;
    for (int i = 0; i < L; ++i) {
      float kk = b2f(kvr[idx]);
      float w  = __expf(fminf(kk, 30.f));
      if (c == 0 && i == 0) w *= tfir;  // time_first seeding at t==0
      float vv = b2f(kvr[idx + 1024]);
      num = d * num + w * vv;
      den = d * den + w;
      idx += KVRN;
    }
  }
  lnum[c][s] = num; lden[c][s] = den;
  __syncthreads();

  // chunk-carry serial scan (64 threads, one per s), in-place: lnum becomes carry-in
  if (threadIdx.x < 64) {
    float rn = 0.f, rd = 0.f;
    for (int cc2 = 0; cc2 < 16; ++cc2) {
      float tn = lnum[cc2][s], tdn = lden[cc2][s];
      lnum[cc2][s] = rn; lden[cc2][s] = rd;
      rn = Dc * rn + tn;
      rd = Dc * rd + tdn;
    }
  }
  __syncthreads();

  // phase 2: replay with carry-in, emit sigmoid(r)*wkv
  num = lnum[c][s]; den = lden[c][s];
  {
    size_t idx = base;
    size_t odx = row0 * CC + ch;
    for (int i = 0; i < L; ++i) {
      float kk = b2f(kvr[idx]);
      float w  = __expf(fminf(kk, 30.f));
      if (c == 0 && i == 0) w *= tfir;
      float vv = b2f(kvr[idx + 1024]);
      num = d * num + w * vv;
      den = d * den + w;
      float o  = num / (den + 1e-6f);
      float rr = b2f(kvr[idx + 2048]);
      float sg = 1.0f / (1.0f + __expf(-rr));
      rwkv[odx] = f2b(sg * o);
      idx += KVRN;
      odx += CC;
    }
  }
}

// ---------------- bf16 MFMA GEMM: C[M,N] = A[M,K] @ Bw[N,K]^T ----------------
// 128x128 tile, BK=32, 2 waves of 64x128 each, XOR-swizzled LDS, global_load_lds staging.
// LDS layout: 16B chunk i holds global (row = i>>2, q = (i&3) ^ ((i>>3)&3)); the XOR
// spreads each quad's 16 rows across all 8 bank-groups (2 lanes/group = free).
// EP=0: bf16 store; EP=1: relu^2 -> bf16; EP=2: fp32 store with residual add
template <int EP>
__global__ __launch_bounds__(128, 2) void gemm_bt(const unsigned short* __restrict__ A,
                                                  const unsigned short* __restrict__ Bw,
                                                  void* __restrict__ outv,
                                                  const float* __restrict__ res,
                                                  int N, int K) {
  __shared__ __align__(16) unsigned short As[128 * 32];
  __shared__ __align__(16) unsigned short Bs[128 * 32];
  const int tid  = threadIdx.x;
  const int w    = tid >> 6;
  const int lane = tid & 63;
  const int bn = blockIdx.x, bm = blockIdx.y;

  // staging: each tile = 512 16B chunks; wave w, instr j covers LDS chunks j*128 + w*64 + lane
  const unsigned short* gA[4];
  const unsigned short* gB[4];
  unsigned short* sA[4];
  unsigned short* sB[4];
#pragma unroll
  for (int j = 0; j < 4; ++j) {
    const int i  = j * 128 + w * 64 + lane;   // LDS chunk index
    const int r  = i >> 2;                    // tile row
    const int qg = (i & 3) ^ ((i >> 3) & 3);  // swizzled k-group
    gA[j] = A  + (size_t)(bm * 128 + r) * K + qg * 8;
    gB[j] = Bw + (size_t)(bn * 128 + r) * K + qg * 8;
    sA[j] = As + i * 8;
    sB[j] = Bs + i * 8;
  }

  const int q   = lane >> 4, r16 = lane & 15;
  const int swz = (r16 >> 1) & 3;
  const int qs  = q ^ swz;  // swizzled chunk-within-row for frag reads

  f32x4 acc[4][8] = {};

  for (int k0 = 0; k0 < K; k0 += 32) {
#pragma unroll
    for (int j = 0; j < 4; ++j) {
      gl_lds16(gA[j], sA[j]);
      gl_lds16(gB[j], sB[j]);
      gA[j] += 32; gB[j] += 32;
    }
    __syncthreads();  // drains vmcnt (loads landed) + all waves arrived

    short8 af[4], bfr[8];
#pragma unroll
    for (int mi = 0; mi < 4; ++mi)
      af[mi] = *(const short8*)(As + ((w * 64 + mi * 16 + r16) * 4 + qs) * 8);
#pragma unroll
    for (int ni = 0; ni < 8; ++ni)
      bfr[ni] = *(const short8*)(Bs + ((ni * 16 + r16) * 4 + qs) * 8);
#pragma unroll
    for (int mi = 0; mi < 4; ++mi)
#pragma unroll
      for (int ni = 0; ni < 8; ++ni)
        acc[mi][ni] = __builtin_amdgcn_mfma_f32_16x16x32_bf16(af[mi], bfr[ni], acc[mi][ni], 0, 0, 0);

    __syncthreads();  // protect LDS before next iteration's async stores
  }

  // epilogue: D[m = quad*4+reg][n = lane&15]; wave w owns rows w*64..w*64+63, all 128 cols
#pragma unroll
  for (int mi = 0; mi < 4; ++mi) {
#pragma unroll
    for (int r = 0; r < 4; ++r) {
      const int grow = bm * 128 + w * 64 + mi * 16 + q * 4 + r;
#pragma unroll
      for (int ni = 0; ni < 8; ++ni) {
        const int gcol = bn * 128 + ni * 16 + r16;
        const size_t idx = (size_t)grow * N + gcol;
        float vv = acc[mi][ni][r];
        if (EP == 2) {
          ((float*)outv)[idx] = res[idx] + vv;
        } else {
          if (EP == 1) { vv = fmaxf(vv, 0.0f); vv = vv * vv; }
          ((unsigned short*)outv)[idx] = f2b(vv);
        }
      }
    }
  }
}

extern "C" void kernel_launch(void* const* d_in, const int* in_sizes, int n_in,
                              void* d_out, int out_size, void* d_ws, size_t ws_size,
                              hipStream_t stream) {
  const float* x    = (const float*)d_in[0];
  const float* td   = (const float*)d_in[1];
  const float* tf   = (const float*)d_in[2];
  const float* Wk   = (const float*)d_in[3];
  const float* Wv   = (const float*)d_in[4];
  const float* Wr   = (const float*)d_in[5];
  const float* Wo   = (const float*)d_in[6];
  const float* Wffk = (const float*)d_in[7];
  const float* Wffv = (const float*)d_in[8];
  const float* g1   = (const float*)d_in[9];
  const float* b1   = (const float*)d_in[10];
  const float* g2   = (const float*)d_in[11];
  const float* b2   = (const float*)d_in[12];
  float* out = (float*)d_out;

  char* ws = (char*)d_ws;
  const size_t MB = 1024ull * 1024ull;
  unsigned short* WkvrB = (unsigned short*)(ws + 0 * MB);   // 6 MB [3072,1024] bf16
  unsigned short* WoB   = (unsigned short*)(ws + 6 * MB);   // 2 MB
  unsigned short* WfkB  = (unsigned short*)(ws + 8 * MB);   // 8 MB
  unsigned short* WfvB  = (unsigned short*)(ws + 16 * MB);  // 8 MB
  unsigned short* xl    = (unsigned short*)(ws + 24 * MB);  // 16 MB (reused as rwkv)
  unsigned short* kvr   = (unsigned short*)(ws + 40 * MB);  // 48 MB [8192,3072] (reused as xl2)
  float*          x2    = (float*)(ws + 88 * MB);           // 32 MB
  unsigned short* hb    = (unsigned short*)(ws + 120 * MB); // 64 MB -> total 184 MB
  unsigned short* rwkv  = xl;   // xl dead after kvr GEMM
  unsigned short* xl2   = kvr;  // kvr dead after WKV

  // weights -> bf16 (k,v,r concatenated into one [3072,1024] buffer)
  cvt_kernel<<<1024, 256, 0, stream>>>(Wk, WkvrB, 1024 * 1024);
  cvt_kernel<<<1024, 256, 0, stream>>>(Wv, WkvrB + 1024 * 1024, 1024 * 1024);
  cvt_kernel<<<1024, 256, 0, stream>>>(Wr, WkvrB + 2 * 1024 * 1024, 1024 * 1024);
  cvt_kernel<<<1024, 256, 0, stream>>>(Wo, WoB, 1024 * 1024);
  cvt_kernel<<<4096, 256, 0, stream>>>(Wffk, WfkB, 4096 * 1024);
  cvt_kernel<<<4096, 256, 0, stream>>>(Wffv, WfvB, 4096 * 1024);

  // LN1
  ln_kernel<<<MROWS, 256, 0, stream>>>(x, g1, b1, xl);

  // fused k|v|r GEMM: kvr[M,3072] = xl @ WkvrB^T
  gemm_bt<0><<<dim3(KVRN / 128, MROWS / 128), 128, 0, stream>>>(xl, WkvrB, kvr, nullptr, KVRN, 1024);

  // WKV + sigmoid(r) fuse
  wkv_kernel<<<4 * HH, 1024, 0, stream>>>(kvr, td, tf, rwkv);

  // x2 = x + rwkv @ Wo^T
  dim3 gk(1024 / 128, MROWS / 128);
  gemm_bt<2><<<gk, 128, 0, stream>>>(rwkv, WoB, x2, x, 1024, 1024);

  // LN2
  ln_kernel<<<MROWS, 256, 0, stream>>>(x2, g2, b2, xl2);

  // h = relu(xl2 @ Wffk^T)^2
  gemm_bt<1><<<dim3(4096 / 128, MROWS / 128), 128, 0, stream>>>(xl2, WfkB, hb, nullptr, 4096, 1024);

  // out = x2 + h @ Wffv^T
  gemm_bt<2><<<gk, 128, 0, stream>>>(hb, WfvB, out, x2, 1024, 4096);
}

// Round 4
// 460.502 us; speedup vs baseline: 1.2286x; 1.1671x over previous
//
#include <hip/hip_runtime.h>
#include <cstdint>
#include <cstddef>

// Problem constants (B=4, T=2048, C=1024, H=16, S=64)
#define TT 2048
#define CC 1024
#define HH 16
#define SS 64
#define MROWS 8192  // B*T
#define KVRN 3072   // fused k|v|r width
#define NCH 32      // WKV chunks per sequence
#define LCH 64      // steps per chunk (TT/NCH)

using short8 = __attribute__((ext_vector_type(8))) short;
using f32x4  = __attribute__((ext_vector_type(4))) float;

__device__ __forceinline__ float b2f(unsigned short u) {
  union { unsigned int i; float f; } c; c.i = ((unsigned int)u) << 16; return c.f;
}
__device__ __forceinline__ unsigned short f2b(float f) {
  union { float f; unsigned int i; } c; c.f = f;
  unsigned int r = c.i + 0x7fffu + ((c.i >> 16) & 1u);  // RNE; inputs finite
  return (unsigned short)(r >> 16);
}

// async global->LDS, 16 bytes per lane (LDS dst = wave-uniform base + lane*16; global per-lane)
typedef const __attribute__((address_space(1))) unsigned int* gas_ptr;
typedef __attribute__((address_space(3))) unsigned int* las_ptr;
__device__ __forceinline__ void gl_lds16(const unsigned short* g, unsigned short* l) {
  __builtin_amdgcn_global_load_lds((gas_ptr)g, (las_ptr)l, 16, 0, 0);
}

// ---------------- all weights fp32 -> bf16, one launch ----------------
// dst layout (elements): [0,3M) Wk|Wv|Wr  [3M,4M) Wo  [4M,8M) Wffk  [8M,12M) Wffv
__global__ __launch_bounds__(256) void cvt_all(const float* __restrict__ Wk,
                                               const float* __restrict__ Wv,
                                               const float* __restrict__ Wr,
                                               const float* __restrict__ Wo,
                                               const float* __restrict__ Wffk,
                                               const float* __restrict__ Wffv,
                                               unsigned short* __restrict__ dst) {
  const size_t M1 = 1048576;
  size_t i = ((size_t)blockIdx.x * 256 + threadIdx.x) * 4;
  const float* src; size_t off;
  if      (i <  1 * M1) { src = Wk;   off = 0;      }
  else if (i <  2 * M1) { src = Wv;   off = 1 * M1; }
  else if (i <  3 * M1) { src = Wr;   off = 2 * M1; }
  else if (i <  4 * M1) { src = Wo;   off = 3 * M1; }
  else if (i <  8 * M1) { src = Wffk; off = 4 * M1; }
  else                  { src = Wffv; off = 8 * M1; }
  float4 v = *(const float4*)(src + (i - off));
  *(ushort4*)(dst + i) = make_ushort4(f2b(v.x), f2b(v.y), f2b(v.z), f2b(v.w));
}

// ---------------- LayerNorm (fp32 in, bf16 out), one block per row ----------------
__global__ __launch_bounds__(256) void ln_kernel(const float* __restrict__ x,
                                                 const float* __restrict__ g,
                                                 const float* __restrict__ bta,
                                                 unsigned short* __restrict__ out) {
  const int row = blockIdx.x;
  const int tid = threadIdx.x;
  const float* xr = x + (size_t)row * CC;
  float4 v = *(const float4*)(xr + tid * 4);
  float s  = v.x + v.y + v.z + v.w;
  float ss = v.x * v.x + v.y * v.y + v.z * v.z + v.w * v.w;
#pragma unroll
  for (int off = 32; off > 0; off >>= 1) {
    s  += __shfl_xor(s, off, 64);
    ss += __shfl_xor(ss, off, 64);
  }
  __shared__ float ls[4], lss[4];
  if ((tid & 63) == 0) { ls[tid >> 6] = s; lss[tid >> 6] = ss; }
  __syncthreads();
  s  = ls[0] + ls[1] + ls[2] + ls[3];
  ss = lss[0] + lss[1] + lss[2] + lss[3];
  const float mean = s * (1.0f / CC);
  const float var  = ss * (1.0f / CC) - mean * mean;
  const float rstd = rsqrtf(var + 1e-5f);
  float4 gv = *(const float4*)(g + tid * 4);
  float4 bv = *(const float4*)(bta + tid * 4);
  ushort4 o = make_ushort4(f2b((v.x - mean) * rstd * gv.x + bv.x),
                           f2b((v.y - mean) * rstd * gv.y + bv.y),
                           f2b((v.z - mean) * rstd * gv.z + bv.z),
                           f2b((v.w - mean) * rstd * gv.w + bv.w));
  *(ushort4*)(out + (size_t)row * CC + tid * 4) = o;
}

// ---------------- WKV hierarchical scan, 2 kernels ----------------
// scratch layout: sums[bh][chunk][0:num/1:den][64] floats
__global__ __launch_bounds__(64) void wkv_local(const unsigned short* __restrict__ kvr,
                                                const float* __restrict__ td,
                                                const float* __restrict__ tfp,
                                                float* __restrict__ scratch) {
  const int blk = blockIdx.x;
  const int bh = blk >> 5, c = blk & (NCH - 1);
  const int b = bh >> 4, h = bh & 15;
  const int s = threadIdx.x;
  const int ch = h * SS + s;
  const float e = __expf(td[ch]);
  const float d = __expf(-e);
  const float tfir = __expf(tfp[ch]);
  size_t idx = ((size_t)b * TT + (size_t)c * LCH) * KVRN + ch;
  float num = 0.f, den = 0.f;
  for (int i = 0; i < LCH; ++i) {
    float w = __expf(fminf(b2f(kvr[idx]), 30.f));
    if (c == 0 && i == 0) w *= tfir;  // time_first seeding at t==0
    float vv = b2f(kvr[idx + 1024]);
    num = d * num + w * vv;
    den = d * den + w;
    idx += KVRN;
  }
  float* o = scratch + ((size_t)bh * NCH + c) * 128;
  o[s] = num; o[64 + s] = den;
}

__global__ __launch_bounds__(64) void wkv_emit(const unsigned short* __restrict__ kvr,
                                               const float* __restrict__ td,
                                               const float* __restrict__ tfp,
                                               const float* __restrict__ scratch,
                                               unsigned short* __restrict__ rwkv) {
  const int blk = blockIdx.x;
  const int bh = blk >> 5, c = blk & (NCH - 1);
  const int b = bh >> 4, h = bh & 15;
  const int s = threadIdx.x;
  const int ch = h * SS + s;
  const float e = __expf(td[ch]);
  const float d = __expf(-e);
  const float Dc = __expf(-e * (float)LCH);
  const float tfir = __expf(tfp[ch]);
  // carry-in = sum_{cc<c} Dc^{c-1-cc} * local(cc)
  float num = 0.f, den = 0.f;
  const float* sc = scratch + (size_t)bh * NCH * 128;
  for (int cc = 0; cc < c; ++cc) {
    num = Dc * num + sc[cc * 128 + s];
    den = Dc * den + sc[cc * 128 + 64 + s];
  }
  size_t idx = ((size_t)b * TT + (size_t)c * LCH) * KVRN + ch;
  size_t odx = ((size_t)b * TT + (size_t)c * LCH) * CC + ch;
  for (int i = 0; i < LCH; ++i) {
    float w = __expf(fminf(b2f(kvr[idx]), 30.f));
    if (c == 0 && i == 0) w *= tfir;
    float vv = b2f(kvr[idx + 1024]);
    num = d * num + w * vv;
    den = d * den + w;
    float o = num / (den + 1e-6f);
    float rr = b2f(kvr[idx + 2048]);
    float sg = 1.0f / (1.0f + __expf(-rr));
    rwkv[odx] = f2b(sg * o);
    idx += KVRN;
    odx += CC;
  }
}

// ---------------- bf16 MFMA GEMM: C[M,N] = A[M,K] @ Bw[N,K]^T ----------------
// 128x128 tile, BK=32, 4 waves of 64x64, XOR-swizzled LDS (0 conflicts), gl_lds staging,
// DOUBLE-BUFFERED: one barrier/iter; prefetch of tile k+1 issued after the barrier and
// drained at the NEXT barrier (one full compute phase of latency hiding).
// 1-D grid, M-grouped (16 bm per group) for L2 reuse of B tiles.
// EP=0: bf16 store; EP=1: relu^2 -> bf16; EP=2: fp32 store with residual add
template <int EP>
__global__ __launch_bounds__(256, 4) void gemm_bt(const unsigned short* __restrict__ A,
                                                  const unsigned short* __restrict__ Bw,
                                                  void* __restrict__ outv,
                                                  const float* __restrict__ res,
                                                  int N, int K) {
  __shared__ __align__(16) unsigned short As[2][128 * 32];
  __shared__ __align__(16) unsigned short Bs[2][128 * 32];
  const int tid = threadIdx.x;

  // grid decode: groups of 16 bm-tiles sweep all bn for L2 reuse
  const int nbn = N >> 7;
  const int per_grp = nbn << 4;
  const int bid = blockIdx.x;
  const int grp = bid / per_grp;
  const int rem = bid - grp * per_grp;
  const int bm = (grp << 4) + (rem & 15);
  const int bn = rem >> 4;

  // staging: 512 16B chunks per tile; thread stages chunks tid and tid+256 for A and B.
  // chunk i holds global (row = i>>2, kgroup = (i&3) ^ ((i>>3)&3)); LDS dst = base + i*16.
  const int ch0 = tid, ch1 = tid + 256;
  const int r0 = ch0 >> 2, q0 = (ch0 & 3) ^ ((ch0 >> 3) & 3);
  const int r1 = ch1 >> 2, q1 = (ch1 & 3) ^ ((ch1 >> 3) & 3);
  const unsigned short* ga0 = A  + (size_t)(bm * 128 + r0) * K + q0 * 8;
  const unsigned short* ga1 = A  + (size_t)(bm * 128 + r1) * K + q1 * 8;
  const unsigned short* gb0 = Bw + (size_t)(bn * 128 + r0) * K + q0 * 8;
  const unsigned short* gb1 = Bw + (size_t)(bn * 128 + r1) * K + q1 * 8;
  const int so0 = ch0 * 8, so1 = ch1 * 8;

  const int lane = tid & 63;
  const int w    = tid >> 6;
  const int q    = lane >> 4, r16 = lane & 15;
  const int qs   = q ^ ((r16 >> 1) & 3);  // swizzled k-group for frag reads
  const int wrow = (w >> 1) * 64, wcol = (w & 1) * 64;

  f32x4 acc[4][4] = {};

  // prologue: stage tile 0 into buffer 0
  gl_lds16(ga0, &As[0][so0]);
  gl_lds16(ga1, &As[0][so1]);
  gl_lds16(gb0, &Bs[0][so0]);
  gl_lds16(gb1, &Bs[0][so1]);
  ga0 += 32; ga1 += 32; gb0 += 32; gb1 += 32;

  int buf = 0;
  for (int k0 = 0; k0 < K; k0 += 32) {
    __syncthreads();  // drains vmcnt: tile-k loads (issued one compute-phase ago) landed;
                      // also: all waves done reading buf^1 from previous iteration
    if (k0 + 32 < K) {
      const int nb = buf ^ 1;
      gl_lds16(ga0, &As[nb][so0]);
      gl_lds16(ga1, &As[nb][so1]);
      gl_lds16(gb0, &Bs[nb][so0]);
      gl_lds16(gb1, &Bs[nb][so1]);
      ga0 += 32; ga1 += 32; gb0 += 32; gb1 += 32;
    }
    const unsigned short* Ab = &As[buf][0];
    const unsigned short* Bb = &Bs[buf][0];
    short8 af[4], bfr[4];
#pragma unroll
    for (int mi = 0; mi < 4; ++mi)
      af[mi] = *(const short8*)(Ab + ((wrow + mi * 16 + r16) * 4 + qs) * 8);
#pragma unroll
    for (int ni = 0; ni < 4; ++ni)
      bfr[ni] = *(const short8*)(Bb + ((wcol + ni * 16 + r16) * 4 + qs) * 8);
#pragma unroll
    for (int mi = 0; mi < 4; ++mi)
#pragma unroll
      for (int ni = 0; ni < 4; ++ni)
        acc[mi][ni] = __builtin_amdgcn_mfma_f32_16x16x32_bf16(af[mi], bfr[ni], acc[mi][ni], 0, 0, 0);
    buf ^= 1;
  }

  // epilogue: D[m = quad*4+reg][n = lane&15]
#pragma unroll
  for (int mi = 0; mi < 4; ++mi) {
#pragma unroll
    for (int r = 0; r < 4; ++r) {
      const int grow = bm * 128 + wrow + mi * 16 + q * 4 + r;
#pragma unroll
      for (int ni = 0; ni < 4; ++ni) {
        const int gcol = bn * 128 + wcol + ni * 16 + r16;
        const size_t idx = (size_t)grow * N + gcol;
        float vv = acc[mi][ni][r];
        if (EP == 2) {
          ((float*)outv)[idx] = res[idx] + vv;
        } else {
          if (EP == 1) { vv = fmaxf(vv, 0.0f); vv = vv * vv; }
          ((unsigned short*)outv)[idx] = f2b(vv);
        }
      }
    }
  }
}

extern "C" void kernel_launch(void* const* d_in, const int* in_sizes, int n_in,
                              void* d_out, int out_size, void* d_ws, size_t ws_size,
                              hipStream_t stream) {
  const float* x    = (const float*)d_in[0];
  const float* td   = (const float*)d_in[1];
  const float* tf   = (const float*)d_in[2];
  const float* Wk   = (const float*)d_in[3];
  const float* Wv   = (const float*)d_in[4];
  const float* Wr   = (const float*)d_in[5];
  const float* Wo   = (const float*)d_in[6];
  const float* Wffk = (const float*)d_in[7];
  const float* Wffv = (const float*)d_in[8];
  const float* g1   = (const float*)d_in[9];
  const float* b1   = (const float*)d_in[10];
  const float* g2   = (const float*)d_in[11];
  const float* b2   = (const float*)d_in[12];
  float* out = (float*)d_out;

  char* ws = (char*)d_ws;
  const size_t MB = 1024ull * 1024ull;
  unsigned short* WB    = (unsigned short*)ws;              // 24 MB contiguous bf16 weights
  unsigned short* WkvrB = WB;                               // [3072,1024]
  unsigned short* WoB   = WB + 3 * 1048576;                 // [1024,1024]
  unsigned short* WfkB  = WB + 4 * 1048576;                 // [4096,1024]
  unsigned short* WfvB  = WB + 8 * 1048576;                 // [1024,4096]
  unsigned short* xl    = (unsigned short*)(ws + 24 * MB);  // 16 MB (reused as rwkv)
  unsigned short* kvr   = (unsigned short*)(ws + 40 * MB);  // 48 MB [8192,3072] (reused as xl2)
  float*          x2    = (float*)(ws + 88 * MB);           // 32 MB
  unsigned short* hb    = (unsigned short*)(ws + 120 * MB); // 64 MB
  float*          wkvS  = (float*)(ws + 184 * MB);          // 1 MB scan scratch -> total 185 MB
  unsigned short* rwkv  = xl;   // xl dead after kvr GEMM
  unsigned short* xl2   = kvr;  // kvr dead after wkv_emit

  // all weights -> bf16 (one launch)
  cvt_all<<<12288, 256, 0, stream>>>(Wk, Wv, Wr, Wo, Wffk, Wffv, WB);

  // LN1
  ln_kernel<<<MROWS, 256, 0, stream>>>(x, g1, b1, xl);

  // fused k|v|r GEMM: kvr[M,3072] = xl @ WkvrB^T   (24*64 = 1536 blocks)
  gemm_bt<0><<<(KVRN / 128) * (MROWS / 128), 256, 0, stream>>>(xl, WkvrB, kvr, nullptr, KVRN, 1024);

  // WKV hierarchical scan + sigmoid(r) fuse
  wkv_local<<<64 * NCH, 64, 0, stream>>>(kvr, td, tf, wkvS);
  wkv_emit<<<64 * NCH, 64, 0, stream>>>(kvr, td, tf, wkvS, rwkv);

  // x2 = x + rwkv @ Wo^T   (8*64 = 512 blocks)
  gemm_bt<2><<<(CC / 128) * (MROWS / 128), 256, 0, stream>>>(rwkv, WoB, x2, x, 1024, 1024);

  // LN2
  ln_kernel<<<MROWS, 256, 0, stream>>>(x2, g2, b2, xl2);

  // h = relu(xl2 @ Wffk^T)^2   (32*64 = 2048 blocks)
  gemm_bt<1><<<(4096 / 128) * (MROWS / 128), 256, 0, stream>>>(xl2, WfkB, hb, nullptr, 4096, 1024);

  // out = x2 + h @ Wffv^T   (512 blocks, K=4096)
  gemm_bt<2><<<(CC / 128) * (MROWS / 128), 256, 0, stream>>>(hb, WfvB, out, x2, 1024, 4096);
}

// Round 5
// 444.386 us; speedup vs baseline: 1.2732x; 1.0363x over previous
//
#include <hip/hip_runtime.h>
#include <cstdint>
#include <cstddef>

// Problem constants (B=4, T=2048, C=1024, H=16, S=64)
#define TT 2048
#define CC 1024
#define HH 16
#define SS 64
#define MROWS 8192  // B*T
#define KVRN 3072   // fused k|v|r width
#define NCH 32      // WKV chunks per sequence
#define LCH 64      // steps per chunk (TT/NCH)

using short8 = __attribute__((ext_vector_type(8))) short;
using f32x4  = __attribute__((ext_vector_type(4))) float;

__device__ __forceinline__ float b2f(unsigned short u) {
  union { unsigned int i; float f; } c; c.i = ((unsigned int)u) << 16; return c.f;
}
__device__ __forceinline__ unsigned short f2b(float f) {
  union { float f; unsigned int i; } c; c.f = f;
  unsigned int r = c.i + 0x7fffu + ((c.i >> 16) & 1u);  // RNE; inputs finite
  return (unsigned short)(r >> 16);
}

// async global->LDS, 16 bytes per lane (LDS dst = wave-uniform base + lane*16; global per-lane)
typedef const __attribute__((address_space(1))) unsigned int* gas_ptr;
typedef __attribute__((address_space(3))) unsigned int* las_ptr;
__device__ __forceinline__ void gl_lds16(const unsigned short* g, unsigned short* l) {
  __builtin_amdgcn_global_load_lds((gas_ptr)g, (las_ptr)l, 16, 0, 0);
}

// ---------------- fused: all weights fp32->bf16 + LN1, one launch ----------------
// blocks [0,12288): cvt; blocks [12288,20480): LN1 row (blockIdx-12288)
__global__ __launch_bounds__(256) void cvt_ln_kernel(const float* __restrict__ Wk,
                                                     const float* __restrict__ Wv,
                                                     const float* __restrict__ Wr,
                                                     const float* __restrict__ Wo,
                                                     const float* __restrict__ Wffk,
                                                     const float* __restrict__ Wffv,
                                                     unsigned short* __restrict__ dst,
                                                     const float* __restrict__ x,
                                                     const float* __restrict__ g,
                                                     const float* __restrict__ bta,
                                                     unsigned short* __restrict__ xlo) {
  const size_t M1 = 1048576;
  const int tid = threadIdx.x;
  if (blockIdx.x < 12288) {
    size_t i = ((size_t)blockIdx.x * 256 + tid) * 4;
    const float* src; size_t off;
    if      (i <  1 * M1) { src = Wk;   off = 0;      }
    else if (i <  2 * M1) { src = Wv;   off = 1 * M1; }
    else if (i <  3 * M1) { src = Wr;   off = 2 * M1; }
    else if (i <  4 * M1) { src = Wo;   off = 3 * M1; }
    else if (i <  8 * M1) { src = Wffk; off = 4 * M1; }
    else                  { src = Wffv; off = 8 * M1; }
    float4 v = *(const float4*)(src + (i - off));
    *(ushort4*)(dst + i) = make_ushort4(f2b(v.x), f2b(v.y), f2b(v.z), f2b(v.w));
    return;
  }
  const int row = blockIdx.x - 12288;
  const float* xr = x + (size_t)row * CC;
  float4 v = *(const float4*)(xr + tid * 4);
  float s  = v.x + v.y + v.z + v.w;
  float ss = v.x * v.x + v.y * v.y + v.z * v.z + v.w * v.w;
#pragma unroll
  for (int off = 32; off > 0; off >>= 1) {
    s  += __shfl_xor(s, off, 64);
    ss += __shfl_xor(ss, off, 64);
  }
  __shared__ float ls[4], lss[4];
  if ((tid & 63) == 0) { ls[tid >> 6] = s; lss[tid >> 6] = ss; }
  __syncthreads();
  s  = ls[0] + ls[1] + ls[2] + ls[3];
  ss = lss[0] + lss[1] + lss[2] + lss[3];
  const float mean = s * (1.0f / CC);
  const float var  = ss * (1.0f / CC) - mean * mean;
  const float rstd = rsqrtf(var + 1e-5f);
  float4 gv = *(const float4*)(g + tid * 4);
  float4 bv = *(const float4*)(bta + tid * 4);
  ushort4 o = make_ushort4(f2b((v.x - mean) * rstd * gv.x + bv.x),
                           f2b((v.y - mean) * rstd * gv.y + bv.y),
                           f2b((v.z - mean) * rstd * gv.z + bv.z),
                           f2b((v.w - mean) * rstd * gv.w + bv.w));
  *(ushort4*)(xlo + (size_t)row * CC + tid * 4) = o;
}

// ---------------- LayerNorm (fp32 in, bf16 out), one block per row ----------------
__global__ __launch_bounds__(256) void ln_kernel(const float* __restrict__ x,
                                                 const float* __restrict__ g,
                                                 const float* __restrict__ bta,
                                                 unsigned short* __restrict__ out) {
  const int row = blockIdx.x;
  const int tid = threadIdx.x;
  const float* xr = x + (size_t)row * CC;
  float4 v = *(const float4*)(xr + tid * 4);
  float s  = v.x + v.y + v.z + v.w;
  float ss = v.x * v.x + v.y * v.y + v.z * v.z + v.w * v.w;
#pragma unroll
  for (int off = 32; off > 0; off >>= 1) {
    s  += __shfl_xor(s, off, 64);
    ss += __shfl_xor(ss, off, 64);
  }
  __shared__ float ls[4], lss[4];
  if ((tid & 63) == 0) { ls[tid >> 6] = s; lss[tid >> 6] = ss; }
  __syncthreads();
  s  = ls[0] + ls[1] + ls[2] + ls[3];
  ss = lss[0] + lss[1] + lss[2] + lss[3];
  const float mean = s * (1.0f / CC);
  const float var  = ss * (1.0f / CC) - mean * mean;
  const float rstd = rsqrtf(var + 1e-5f);
  float4 gv = *(const float4*)(g + tid * 4);
  float4 bv = *(const float4*)(bta + tid * 4);
  ushort4 o = make_ushort4(f2b((v.x - mean) * rstd * gv.x + bv.x),
                           f2b((v.y - mean) * rstd * gv.y + bv.y),
                           f2b((v.z - mean) * rstd * gv.z + bv.z),
                           f2b((v.w - mean) * rstd * gv.w + bv.w));
  *(ushort4*)(out + (size_t)row * CC + tid * 4) = o;
}

// ---------------- WKV hierarchical scan, 2 kernels ----------------
__global__ __launch_bounds__(64) void wkv_local(const unsigned short* __restrict__ kvr,
                                                const float* __restrict__ td,
                                                const float* __restrict__ tfp,
                                                float* __restrict__ scratch) {
  const int blk = blockIdx.x;
  const int bh = blk >> 5, c = blk & (NCH - 1);
  const int b = bh >> 4, h = bh & 15;
  const int s = threadIdx.x;
  const int ch = h * SS + s;
  const float e = __expf(td[ch]);
  const float d = __expf(-e);
  const float tfir = __expf(tfp[ch]);
  size_t idx = ((size_t)b * TT + (size_t)c * LCH) * KVRN + ch;
  float num = 0.f, den = 0.f;
  for (int i = 0; i < LCH; ++i) {
    float w = __expf(fminf(b2f(kvr[idx]), 30.f));
    if (c == 0 && i == 0) w *= tfir;  // time_first seeding at t==0
    float vv = b2f(kvr[idx + 1024]);
    num = d * num + w * vv;
    den = d * den + w;
    idx += KVRN;
  }
  float* o = scratch + ((size_t)bh * NCH + c) * 128;
  o[s] = num; o[64 + s] = den;
}

__global__ __launch_bounds__(64) void wkv_emit(const unsigned short* __restrict__ kvr,
                                               const float* __restrict__ td,
                                               const float* __restrict__ tfp,
                                               const float* __restrict__ scratch,
                                               unsigned short* __restrict__ rwkv) {
  const int blk = blockIdx.x;
  const int bh = blk >> 5, c = blk & (NCH - 1);
  const int b = bh >> 4, h = bh & 15;
  const int s = threadIdx.x;
  const int ch = h * SS + s;
  const float e = __expf(td[ch]);
  const float d = __expf(-e);
  const float Dc = __expf(-e * (float)LCH);
  const float tfir = __expf(tfp[ch]);
  float num = 0.f, den = 0.f;
  const float* sc = scratch + (size_t)bh * NCH * 128;
  for (int cc = 0; cc < c; ++cc) {
    num = Dc * num + sc[cc * 128 + s];
    den = Dc * den + sc[cc * 128 + 64 + s];
  }
  size_t idx = ((size_t)b * TT + (size_t)c * LCH) * KVRN + ch;
  size_t odx = ((size_t)b * TT + (size_t)c * LCH) * CC + ch;
  for (int i = 0; i < LCH; ++i) {
    float w = __expf(fminf(b2f(kvr[idx]), 30.f));
    if (c == 0 && i == 0) w *= tfir;
    float vv = b2f(kvr[idx + 1024]);
    num = d * num + w * vv;
    den = d * den + w;
    float o = num / (den + 1e-6f);
    float rr = b2f(kvr[idx + 2048]);
    float sg = 1.0f / (1.0f + __expf(-rr));
    rwkv[odx] = f2b(sg * o);
    idx += KVRN;
    odx += CC;
  }
}

// ---------------- bf16 MFMA GEMM: C[M,N] = A[M,K] @ Bw[N,K]^T ----------------
// 128x128 tile, BK=32, 4 waves of 64x64, XOR-swizzled LDS (0 conflicts), gl_lds staging.
// TRIPLE-BUFFERED, prefetch distance 2: during iter i we issue tile i+2, so every
// tile's loads get ~2 compute phases in flight before the barrier's vmcnt(0) drain.
// sched_barrier(0) pins the prefetch issue point (compiler must not sink it).
// 1-D grid, M-grouped (16 bm per group) for L2 reuse of B tiles.
// EP=0: bf16 store; EP=1: relu^2 -> bf16; EP=2: fp32 store with residual add
template <int EP>
__global__ __launch_bounds__(256, 3) void gemm_bt(const unsigned short* __restrict__ A,
                                                  const unsigned short* __restrict__ Bw,
                                                  void* __restrict__ outv,
                                                  const float* __restrict__ res,
                                                  int N, int K) {
  __shared__ __align__(16) unsigned short As[3][128 * 32];
  __shared__ __align__(16) unsigned short Bs[3][128 * 32];
  const int tid = threadIdx.x;

  // grid decode: groups of 16 bm-tiles sweep all bn for L2 reuse
  const int nbn = N >> 7;
  const int per_grp = nbn << 4;
  const int bid = blockIdx.x;
  const int grp = bid / per_grp;
  const int rem = bid - grp * per_grp;
  const int bm = (grp << 4) + (rem & 15);
  const int bn = rem >> 4;

  // staging: 512 16B chunks per tile; thread stages chunks tid and tid+256 for A and B.
  // chunk i holds global (row = i>>2, kgroup = (i&3) ^ ((i>>3)&3)); LDS dst = base + i*16.
  const int ch0 = tid, ch1 = tid + 256;
  const int r0 = ch0 >> 2, q0 = (ch0 & 3) ^ ((ch0 >> 3) & 3);
  const int r1 = ch1 >> 2, q1 = (ch1 & 3) ^ ((ch1 >> 3) & 3);
  const unsigned short* ga0 = A  + (size_t)(bm * 128 + r0) * K + q0 * 8;
  const unsigned short* ga1 = A  + (size_t)(bm * 128 + r1) * K + q1 * 8;
  const unsigned short* gb0 = Bw + (size_t)(bn * 128 + r0) * K + q0 * 8;
  const unsigned short* gb1 = Bw + (size_t)(bn * 128 + r1) * K + q1 * 8;
  const int so0 = ch0 * 8, so1 = ch1 * 8;

  const int lane = tid & 63;
  const int w    = tid >> 6;
  const int q    = lane >> 4, r16 = lane & 15;
  const int qs   = q ^ ((r16 >> 1) & 3);  // swizzled k-group for frag reads
  const int wrow = (w >> 1) * 64, wcol = (w & 1) * 64;

  f32x4 acc[4][4] = {};

  auto stage = [&](int b3) {
    gl_lds16(ga0, &As[b3][so0]);
    gl_lds16(ga1, &As[b3][so1]);
    gl_lds16(gb0, &Bs[b3][so0]);
    gl_lds16(gb1, &Bs[b3][so1]);
    ga0 += 32; ga1 += 32; gb0 += 32; gb1 += 32;
  };

  const int iters = K >> 5;  // >= 32 always here
  // prologue: tiles 0,1 into buffers 0,1
  stage(0);
  stage(1);

  int cb = 0, pb = 2;
  for (int i = 0; i < iters; ++i) {
    __syncthreads();  // vmcnt(0) drain: tile i (issued ~2 phases ago) has landed;
                      // all waves done reading buffer pb (last read in iter i-1)
    if (i + 2 < iters) stage(pb);
    __builtin_amdgcn_sched_barrier(0);  // pin prefetch issue before the compute phase

    const unsigned short* Ab = &As[cb][0];
    const unsigned short* Bb = &Bs[cb][0];
    short8 af[4], bfr[4];
#pragma unroll
    for (int mi = 0; mi < 4; ++mi)
      af[mi] = *(const short8*)(Ab + ((wrow + mi * 16 + r16) * 4 + qs) * 8);
#pragma unroll
    for (int ni = 0; ni < 4; ++ni)
      bfr[ni] = *(const short8*)(Bb + ((wcol + ni * 16 + r16) * 4 + qs) * 8);
#pragma unroll
    for (int mi = 0; mi < 4; ++mi)
#pragma unroll
      for (int ni = 0; ni < 4; ++ni)
        acc[mi][ni] = __builtin_amdgcn_mfma_f32_16x16x32_bf16(af[mi], bfr[ni], acc[mi][ni], 0, 0, 0);

    cb = (cb == 2) ? 0 : cb + 1;
    pb = (pb == 2) ? 0 : pb + 1;
  }

  // epilogue: D[m = quad*4+reg][n = lane&15]
#pragma unroll
  for (int mi = 0; mi < 4; ++mi) {
#pragma unroll
    for (int r = 0; r < 4; ++r) {
      const int grow = bm * 128 + wrow + mi * 16 + q * 4 + r;
#pragma unroll
      for (int ni = 0; ni < 4; ++ni) {
        const int gcol = bn * 128 + wcol + ni * 16 + r16;
        const size_t idx = (size_t)grow * N + gcol;
        float vv = acc[mi][ni][r];
        if (EP == 2) {
          ((float*)outv)[idx] = res[idx] + vv;
        } else {
          if (EP == 1) { vv = fmaxf(vv, 0.0f); vv = vv * vv; }
          ((unsigned short*)outv)[idx] = f2b(vv);
        }
      }
    }
  }
}

extern "C" void kernel_launch(void* const* d_in, const int* in_sizes, int n_in,
                              void* d_out, int out_size, void* d_ws, size_t ws_size,
                              hipStream_t stream) {
  const float* x    = (const float*)d_in[0];
  const float* td   = (const float*)d_in[1];
  const float* tf   = (const float*)d_in[2];
  const float* Wk   = (const float*)d_in[3];
  const float* Wv   = (const float*)d_in[4];
  const float* Wr   = (const float*)d_in[5];
  const float* Wo   = (const float*)d_in[6];
  const float* Wffk = (const float*)d_in[7];
  const float* Wffv = (const float*)d_in[8];
  const float* g1   = (const float*)d_in[9];
  const float* b1   = (const float*)d_in[10];
  const float* g2   = (const float*)d_in[11];
  const float* b2   = (const float*)d_in[12];
  float* out = (float*)d_out;

  char* ws = (char*)d_ws;
  const size_t MB = 1024ull * 1024ull;
  unsigned short* WB    = (unsigned short*)ws;              // 24 MB contiguous bf16 weights
  unsigned short* WkvrB = WB;                               // [3072,1024]
  unsigned short* WoB   = WB + 3 * 1048576;                 // [1024,1024]
  unsigned short* WfkB  = WB + 4 * 1048576;                 // [4096,1024]
  unsigned short* WfvB  = WB + 8 * 1048576;                 // [1024,4096]
  unsigned short* xl    = (unsigned short*)(ws + 24 * MB);  // 16 MB (reused as rwkv)
  unsigned short* kvr   = (unsigned short*)(ws + 40 * MB);  // 48 MB [8192,3072] (reused as xl2)
  float*          x2    = (float*)(ws + 88 * MB);           // 32 MB
  unsigned short* hb    = (unsigned short*)(ws + 120 * MB); // 64 MB
  float*          wkvS  = (float*)(ws + 184 * MB);          // 1 MB scan scratch -> total 185 MB
  unsigned short* rwkv  = xl;   // xl dead after kvr GEMM
  unsigned short* xl2   = kvr;  // kvr dead after wkv_emit

  // weights -> bf16 + LN1, fused single launch
  cvt_ln_kernel<<<12288 + MROWS, 256, 0, stream>>>(Wk, Wv, Wr, Wo, Wffk, Wffv, WB,
                                                   x, g1, b1, xl);

  // fused k|v|r GEMM: kvr[M,3072] = xl @ WkvrB^T   (1536 blocks)
  gemm_bt<0><<<(KVRN / 128) * (MROWS / 128), 256, 0, stream>>>(xl, WkvrB, kvr, nullptr, KVRN, 1024);

  // WKV hierarchical scan + sigmoid(r) fuse
  wkv_local<<<64 * NCH, 64, 0, stream>>>(kvr, td, tf, wkvS);
  wkv_emit<<<64 * NCH, 64, 0, stream>>>(kvr, td, tf, wkvS, rwkv);

  // x2 = x + rwkv @ Wo^T   (512 blocks)
  gemm_bt<2><<<(CC / 128) * (MROWS / 128), 256, 0, stream>>>(rwkv, WoB, x2, x, 1024, 1024);

  // LN2
  ln_kernel<<<MROWS, 256, 0, stream>>>(x2, g2, b2, xl2);

  // h = relu(xl2 @ Wffk^T)^2   (2048 blocks)
  gemm_bt<1><<<(4096 / 128) * (MROWS / 128), 256, 0, stream>>>(xl2, WfkB, hb, nullptr, 4096, 1024);

  // out = x2 + h @ Wffv^T   (512 blocks, K=4096)
  gemm_bt<2><<<(CC / 128) * (MROWS / 128), 256, 0, stream>>>(hb, WfvB, out, x2, 1024, 4096);
}

// Round 6
// 438.377 us; speedup vs baseline: 1.2906x; 1.0137x over previous
//
#include <hip/hip_runtime.h>
#include <cstdint>
#include <cstddef>

// Problem constants (B=4, T=2048, C=1024, H=16, S=64)
#define TT 2048
#define CC 1024
#define HH 16
#define SS 64
#define MROWS 8192  // B*T
#define KVRN 3072   // fused k|v|r width
#define NCH 32      // WKV chunks per sequence
#define LCH 64      // steps per chunk (TT/NCH)

using short8 = __attribute__((ext_vector_type(8))) short;
using f32x4  = __attribute__((ext_vector_type(4))) float;

__device__ __forceinline__ float b2f(unsigned short u) {
  union { unsigned int i; float f; } c; c.i = ((unsigned int)u) << 16; return c.f;
}
__device__ __forceinline__ unsigned short f2b(float f) {
  union { float f; unsigned int i; } c; c.f = f;
  unsigned int r = c.i + 0x7fffu + ((c.i >> 16) & 1u);  // RNE; inputs finite
  return (unsigned short)(r >> 16);
}

// async global->LDS, 16 bytes per lane (LDS dst = wave-uniform base + lane*16; global per-lane)
typedef const __attribute__((address_space(1))) unsigned int* gas_ptr;
typedef __attribute__((address_space(3))) unsigned int* las_ptr;
__device__ __forceinline__ void gl_lds16(const unsigned short* g, unsigned short* l) {
  __builtin_amdgcn_global_load_lds((gas_ptr)g, (las_ptr)l, 16, 0, 0);
}

// ---------------- fused: all weights fp32->bf16 + LN1, one launch ----------------
// blocks [0,12288): cvt; blocks [12288,20480): LN1 row (blockIdx-12288)
__global__ __launch_bounds__(256) void cvt_ln_kernel(const float* __restrict__ Wk,
                                                     const float* __restrict__ Wv,
                                                     const float* __restrict__ Wr,
                                                     const float* __restrict__ Wo,
                                                     const float* __restrict__ Wffk,
                                                     const float* __restrict__ Wffv,
                                                     unsigned short* __restrict__ dst,
                                                     const float* __restrict__ x,
                                                     const float* __restrict__ g,
                                                     const float* __restrict__ bta,
                                                     unsigned short* __restrict__ xlo) {
  const size_t M1 = 1048576;
  const int tid = threadIdx.x;
  if (blockIdx.x < 12288) {
    size_t i = ((size_t)blockIdx.x * 256 + tid) * 4;
    const float* src; size_t off;
    if      (i <  1 * M1) { src = Wk;   off = 0;      }
    else if (i <  2 * M1) { src = Wv;   off = 1 * M1; }
    else if (i <  3 * M1) { src = Wr;   off = 2 * M1; }
    else if (i <  4 * M1) { src = Wo;   off = 3 * M1; }
    else if (i <  8 * M1) { src = Wffk; off = 4 * M1; }
    else                  { src = Wffv; off = 8 * M1; }
    float4 v = *(const float4*)(src + (i - off));
    *(ushort4*)(dst + i) = make_ushort4(f2b(v.x), f2b(v.y), f2b(v.z), f2b(v.w));
    return;
  }
  const int row = blockIdx.x - 12288;
  const float* xr = x + (size_t)row * CC;
  float4 v = *(const float4*)(xr + tid * 4);
  float s  = v.x + v.y + v.z + v.w;
  float ss = v.x * v.x + v.y * v.y + v.z * v.z + v.w * v.w;
#pragma unroll
  for (int off = 32; off > 0; off >>= 1) {
    s  += __shfl_xor(s, off, 64);
    ss += __shfl_xor(ss, off, 64);
  }
  __shared__ float ls[4], lss[4];
  if ((tid & 63) == 0) { ls[tid >> 6] = s; lss[tid >> 6] = ss; }
  __syncthreads();
  s  = ls[0] + ls[1] + ls[2] + ls[3];
  ss = lss[0] + lss[1] + lss[2] + lss[3];
  const float mean = s * (1.0f / CC);
  const float var  = ss * (1.0f / CC) - mean * mean;
  const float rstd = rsqrtf(var + 1e-5f);
  float4 gv = *(const float4*)(g + tid * 4);
  float4 bv = *(const float4*)(bta + tid * 4);
  ushort4 o = make_ushort4(f2b((v.x - mean) * rstd * gv.x + bv.x),
                           f2b((v.y - mean) * rstd * gv.y + bv.y),
                           f2b((v.z - mean) * rstd * gv.z + bv.z),
                           f2b((v.w - mean) * rstd * gv.w + bv.w));
  *(ushort4*)(xlo + (size_t)row * CC + tid * 4) = o;
}

// ---------------- LayerNorm (fp32 in, bf16 out), one block per row ----------------
__global__ __launch_bounds__(256) void ln_kernel(const float* __restrict__ x,
                                                 const float* __restrict__ g,
                                                 const float* __restrict__ bta,
                                                 unsigned short* __restrict__ out) {
  const int row = blockIdx.x;
  const int tid = threadIdx.x;
  const float* xr = x + (size_t)row * CC;
  float4 v = *(const float4*)(xr + tid * 4);
  float s  = v.x + v.y + v.z + v.w;
  float ss = v.x * v.x + v.y * v.y + v.z * v.z + v.w * v.w;
#pragma unroll
  for (int off = 32; off > 0; off >>= 1) {
    s  += __shfl_xor(s, off, 64);
    ss += __shfl_xor(ss, off, 64);
  }
  __shared__ float ls[4], lss[4];
  if ((tid & 63) == 0) { ls[tid >> 6] = s; lss[tid >> 6] = ss; }
  __syncthreads();
  s  = ls[0] + ls[1] + ls[2] + ls[3];
  ss = lss[0] + lss[1] + lss[2] + lss[3];
  const float mean = s * (1.0f / CC);
  const float var  = ss * (1.0f / CC) - mean * mean;
  const float rstd = rsqrtf(var + 1e-5f);
  float4 gv = *(const float4*)(g + tid * 4);
  float4 bv = *(const float4*)(bta + tid * 4);
  ushort4 o = make_ushort4(f2b((v.x - mean) * rstd * gv.x + bv.x),
                           f2b((v.y - mean) * rstd * gv.y + bv.y),
                           f2b((v.z - mean) * rstd * gv.z + bv.z),
                           f2b((v.w - mean) * rstd * gv.w + bv.w));
  *(ushort4*)(out + (size_t)row * CC + tid * 4) = o;
}

// ---------------- WKV hierarchical scan, 2 kernels ----------------
__global__ __launch_bounds__(64) void wkv_local(const unsigned short* __restrict__ kvr,
                                                const float* __restrict__ td,
                                                const float* __restrict__ tfp,
                                                float* __restrict__ scratch) {
  const int blk = blockIdx.x;
  const int bh = blk >> 5, c = blk & (NCH - 1);
  const int b = bh >> 4, h = bh & 15;
  const int s = threadIdx.x;
  const int ch = h * SS + s;
  const float e = __expf(td[ch]);
  const float d = __expf(-e);
  const float tfir = __expf(tfp[ch]);
  size_t idx = ((size_t)b * TT + (size_t)c * LCH) * KVRN + ch;
  float num = 0.f, den = 0.f;
  for (int i = 0; i < LCH; ++i) {
    float w = __expf(fminf(b2f(kvr[idx]), 30.f));
    if (c == 0 && i == 0) w *= tfir;  // time_first seeding at t==0
    float vv = b2f(kvr[idx + 1024]);
    num = d * num + w * vv;
    den = d * den + w;
    idx += KVRN;
  }
  float* o = scratch + ((size_t)bh * NCH + c) * 128;
  o[s] = num; o[64 + s] = den;
}

__global__ __launch_bounds__(64) void wkv_emit(const unsigned short* __restrict__ kvr,
                                               const float* __restrict__ td,
                                               const float* __restrict__ tfp,
                                               const float* __restrict__ scratch,
                                               unsigned short* __restrict__ rwkv) {
  const int blk = blockIdx.x;
  const int bh = blk >> 5, c = blk & (NCH - 1);
  const int b = bh >> 4, h = bh & 15;
  const int s = threadIdx.x;
  const int ch = h * SS + s;
  const float e = __expf(td[ch]);
  const float d = __expf(-e);
  const float Dc = __expf(-e * (float)LCH);
  const float tfir = __expf(tfp[ch]);
  float num = 0.f, den = 0.f;
  const float* sc = scratch + (size_t)bh * NCH * 128;
  for (int cc = 0; cc < c; ++cc) {
    num = Dc * num + sc[cc * 128 + s];
    den = Dc * den + sc[cc * 128 + 64 + s];
  }
  size_t idx = ((size_t)b * TT + (size_t)c * LCH) * KVRN + ch;
  size_t odx = ((size_t)b * TT + (size_t)c * LCH) * CC + ch;
  for (int i = 0; i < LCH; ++i) {
    float w = __expf(fminf(b2f(kvr[idx]), 30.f));
    if (c == 0 && i == 0) w *= tfir;
    float vv = b2f(kvr[idx + 1024]);
    num = d * num + w * vv;
    den = d * den + w;
    float o = num / (den + 1e-6f);
    float rr = b2f(kvr[idx + 2048]);
    float sg = 1.0f / (1.0f + __expf(-rr));
    rwkv[odx] = f2b(sg * o);
    idx += KVRN;
    odx += CC;
  }
}

// ---------------- bf16 MFMA GEMM: C[M,N] = A[M,K] @ Bw[N,K]^T ----------------
// 128x128 tile, BK=32, 4 waves of 64x64, XOR-swizzled LDS (0 conflicts), gl_lds staging.
// AITER-style K-loop: 3 LDS buffers, prefetch distance 2, RAW s_barrier (inline asm, no
// compiler vmcnt(0) drain) preceded by explicit s_waitcnt vmcnt(4). Each wave has <=8
// gl_lds outstanding; vmcnt(4) waits only the 4 oldest (= tile i, in-order completion),
// leaving the newer prefetches in flight ACROSS the barrier. Every wave performs the
// same wait before the barrier, so after barrier-release tile i is fully in LDS.
// ds_reads of tile i-1 are consumed by MFMAs (lgkm-waited) before a wave reaches the
// next barrier, so buffer reuse (i+2 overwrites i-1's buffer) is race-free.
// 1-D grid, M-grouped (16 bm per group) for L2 reuse of B tiles.
// EP=0: bf16 store; EP=1: relu^2 -> bf16; EP=2: fp32 store with residual add
template <int EP>
__global__ __launch_bounds__(256, 3) void gemm_bt(const unsigned short* __restrict__ A,
                                                  const unsigned short* __restrict__ Bw,
                                                  void* __restrict__ outv,
                                                  const float* __restrict__ res,
                                                  int N, int K) {
  __shared__ __align__(16) unsigned short As[3][128 * 32];
  __shared__ __align__(16) unsigned short Bs[3][128 * 32];
  const int tid = threadIdx.x;

  // grid decode: groups of 16 bm-tiles sweep all bn for L2 reuse
  const int nbn = N >> 7;
  const int per_grp = nbn << 4;
  const int bid = blockIdx.x;
  const int grp = bid / per_grp;
  const int rem = bid - grp * per_grp;
  const int bm = (grp << 4) + (rem & 15);
  const int bn = rem >> 4;

  // staging: 512 16B chunks per tile; thread stages chunks tid and tid+256 for A and B.
  // chunk i holds global (row = i>>2, kgroup = (i&3) ^ ((i>>3)&3)); LDS dst = base + i*16.
  const int ch0 = tid, ch1 = tid + 256;
  const int r0 = ch0 >> 2, q0 = (ch0 & 3) ^ ((ch0 >> 3) & 3);
  const int r1 = ch1 >> 2, q1 = (ch1 & 3) ^ ((ch1 >> 3) & 3);
  const unsigned short* ga0 = A  + (size_t)(bm * 128 + r0) * K + q0 * 8;
  const unsigned short* ga1 = A  + (size_t)(bm * 128 + r1) * K + q1 * 8;
  const unsigned short* gb0 = Bw + (size_t)(bn * 128 + r0) * K + q0 * 8;
  const unsigned short* gb1 = Bw + (size_t)(bn * 128 + r1) * K + q1 * 8;
  const int so0 = ch0 * 8, so1 = ch1 * 8;

  const int lane = tid & 63;
  const int w    = tid >> 6;
  const int q    = lane >> 4, r16 = lane & 15;
  const int qs   = q ^ ((r16 >> 1) & 3);  // swizzled k-group for frag reads
  const int wrow = (w >> 1) * 64, wcol = (w & 1) * 64;

  f32x4 acc[4][4] = {};

  auto stage = [&](int b3) {
    gl_lds16(ga0, &As[b3][so0]);
    gl_lds16(ga1, &As[b3][so1]);
    gl_lds16(gb0, &Bs[b3][so0]);
    gl_lds16(gb1, &Bs[b3][so1]);
    ga0 += 32; ga1 += 32; gb0 += 32; gb1 += 32;
  };

  const int iters = K >> 5;  // >= 32 always here
  // prologue: tiles 0,1 into buffers 0,1 (8 gl_lds outstanding per wave)
  stage(0);
  stage(1);

  int cb = 0, pb = 2;
  for (int i = 0; i < iters; ++i) {
    // wait this wave's 4 oldest loads (tile i) -> landed; newer 4 stay in flight.
    // imm 0xF74: vmcnt=4, expcnt=7 (none), lgkmcnt=15 (none)
    __builtin_amdgcn_s_waitcnt(0x0F74);
    __builtin_amdgcn_sched_barrier(0);
    asm volatile("s_barrier");          // raw barrier: NO vmcnt(0) drain
    __builtin_amdgcn_sched_barrier(0);
    if (i + 2 < iters) stage(pb);       // tile i+2: in flight for ~2 compute phases

    const unsigned short* Ab = &As[cb][0];
    const unsigned short* Bb = &Bs[cb][0];
    short8 af[4], bfr[4];
#pragma unroll
    for (int mi = 0; mi < 4; ++mi)
      af[mi] = *(const short8*)(Ab + ((wrow + mi * 16 + r16) * 4 + qs) * 8);
#pragma unroll
    for (int ni = 0; ni < 4; ++ni)
      bfr[ni] = *(const short8*)(Bb + ((wcol + ni * 16 + r16) * 4 + qs) * 8);
#pragma unroll
    for (int mi = 0; mi < 4; ++mi)
#pragma unroll
      for (int ni = 0; ni < 4; ++ni)
        acc[mi][ni] = __builtin_amdgcn_mfma_f32_16x16x32_bf16(af[mi], bfr[ni], acc[mi][ni], 0, 0, 0);

    cb = (cb == 2) ? 0 : cb + 1;
    pb = (pb == 2) ? 0 : pb + 1;
  }

  // epilogue: D[m = quad*4+reg][n = lane&15]
#pragma unroll
  for (int mi = 0; mi < 4; ++mi) {
#pragma unroll
    for (int r = 0; r < 4; ++r) {
      const int grow = bm * 128 + wrow + mi * 16 + q * 4 + r;
#pragma unroll
      for (int ni = 0; ni < 4; ++ni) {
        const int gcol = bn * 128 + wcol + ni * 16 + r16;
        const size_t idx = (size_t)grow * N + gcol;
        float vv = acc[mi][ni][r];
        if (EP == 2) {
          ((float*)outv)[idx] = res[idx] + vv;
        } else {
          if (EP == 1) { vv = fmaxf(vv, 0.0f); vv = vv * vv; }
          ((unsigned short*)outv)[idx] = f2b(vv);
        }
      }
    }
  }
}

extern "C" void kernel_launch(void* const* d_in, const int* in_sizes, int n_in,
                              void* d_out, int out_size, void* d_ws, size_t ws_size,
                              hipStream_t stream) {
  const float* x    = (const float*)d_in[0];
  const float* td   = (const float*)d_in[1];
  const float* tf   = (const float*)d_in[2];
  const float* Wk   = (const float*)d_in[3];
  const float* Wv   = (const float*)d_in[4];
  const float* Wr   = (const float*)d_in[5];
  const float* Wo   = (const float*)d_in[6];
  const float* Wffk = (const float*)d_in[7];
  const float* Wffv = (const float*)d_in[8];
  const float* g1   = (const float*)d_in[9];
  const float* b1   = (const float*)d_in[10];
  const float* g2   = (const float*)d_in[11];
  const float* b2   = (const float*)d_in[12];
  float* out = (float*)d_out;

  char* ws = (char*)d_ws;
  const size_t MB = 1024ull * 1024ull;
  unsigned short* WB    = (unsigned short*)ws;              // 24 MB contiguous bf16 weights
  unsigned short* WkvrB = WB;                               // [3072,1024]
  unsigned short* WoB   = WB + 3 * 1048576;                 // [1024,1024]
  unsigned short* WfkB  = WB + 4 * 1048576;                 // [4096,1024]
  unsigned short* WfvB  = WB + 8 * 1048576;                 // [1024,4096]
  unsigned short* xl    = (unsigned short*)(ws + 24 * MB);  // 16 MB (reused as rwkv)
  unsigned short* kvr   = (unsigned short*)(ws + 40 * MB);  // 48 MB [8192,3072] (reused as xl2)
  float*          x2    = (float*)(ws + 88 * MB);           // 32 MB
  unsigned short* hb    = (unsigned short*)(ws + 120 * MB); // 64 MB
  float*          wkvS  = (float*)(ws + 184 * MB);          // 1 MB scan scratch -> total 185 MB
  unsigned short* rwkv  = xl;   // xl dead after kvr GEMM
  unsigned short* xl2   = kvr;  // kvr dead after wkv_emit

  // weights -> bf16 + LN1, fused single launch
  cvt_ln_kernel<<<12288 + MROWS, 256, 0, stream>>>(Wk, Wv, Wr, Wo, Wffk, Wffv, WB,
                                                   x, g1, b1, xl);

  // fused k|v|r GEMM: kvr[M,3072] = xl @ WkvrB^T   (1536 blocks)
  gemm_bt<0><<<(KVRN / 128) * (MROWS / 128), 256, 0, stream>>>(xl, WkvrB, kvr, nullptr, KVRN, 1024);

  // WKV hierarchical scan + sigmoid(r) fuse
  wkv_local<<<64 * NCH, 64, 0, stream>>>(kvr, td, tf, wkvS);
  wkv_emit<<<64 * NCH, 64, 0, stream>>>(kvr, td, tf, wkvS, rwkv);

  // x2 = x + rwkv @ Wo^T   (512 blocks)
  gemm_bt<2><<<(CC / 128) * (MROWS / 128), 256, 0, stream>>>(rwkv, WoB, x2, x, 1024, 1024);

  // LN2
  ln_kernel<<<MROWS, 256, 0, stream>>>(x2, g2, b2, xl2);

  // h = relu(xl2 @ Wffk^T)^2   (2048 blocks)
  gemm_bt<1><<<(4096 / 128) * (MROWS / 128), 256, 0, stream>>>(xl2, WfkB, hb, nullptr, 4096, 1024);

  // out = x2 + h @ Wffv^T   (512 blocks, K=4096)
  gemm_bt<2><<<(CC / 128) * (MROWS / 128), 256, 0, stream>>>(hb, WfvB, out, x2, 1024, 4096);
}